// Round 2
// baseline (155.330 us; speedup 1.0000x reference)
//
#include <hip/hip_runtime.h>
#include <hip/hip_bf16.h>

#define Bv 32
#define Dv 512
#define Kv 64
#define Nv 1024
#define EPSv 1e-12f

typedef __attribute__((ext_vector_type(8))) short bf16x8;
typedef __attribute__((ext_vector_type(4))) float f32x4;

// fp32 -> bf16 (RNE), bit-level
__device__ __forceinline__ unsigned short f2b(float f) {
  union { float f; unsigned u; } v; v.f = f;
  unsigned r = v.u + 0x7fffu + ((v.u >> 16) & 1u);
  return (unsigned short)(r >> 16);
}
__device__ __forceinline__ unsigned pack2(float a, float b) {
  return (unsigned)f2b(a) | ((unsigned)f2b(b) << 16);
}

// ---------------------------------------------------------------------------
// Kernel W: convert conv_w (K x D fp32) -> bf16. 32 blocks x 256 thr.
// ---------------------------------------------------------------------------
__global__ __launch_bounds__(256) void wconv(const float* __restrict__ w,
                                             unsigned short* __restrict__ wbf) {
  int i = (blockIdx.x * 256 + threadIdx.x) * 4;
  float4 v = *(const float4*)&w[i];
  uint2 o = make_uint2(pack2(v.x, v.y), pack2(v.z, v.w));
  *(uint2*)&wbf[i] = o;
}

// ---------------------------------------------------------------------------
// Kernel 1 (fused T+A), unchanged from R6:
//  - NO xbf writeback (vlad kernel re-reads fp32 x from L3 instead)
//  - staging LDS writes rotated by s=(lo>>1)&3 to break the 8-way bank
//    conflict
// Grid (N/64, B) = (16, 32) = 512 blocks, 512 threads (8 waves).
// ---------------------------------------------------------------------------
__global__ __launch_bounds__(512) void fused_scores(
    const float* __restrict__ x, const unsigned short* __restrict__ wbf,
    unsigned short* __restrict__ assign, float* __restrict__ asum) {
  __shared__ unsigned short xT[64 * 520];   // [n][d], pitch 520 shorts (1040B)
  __shared__ float redmax[4][64];
  __shared__ float redsum[4][64];

  const int t = threadIdx.x;   // 0..511
  const int b = blockIdx.y;
  const int n0 = blockIdx.x * 64;

  // ---------------- staging ----------------
  {
    const int lo = t & 15;     // n-quad
    const int hi = t >> 4;     // 0..31 (d-pair subindex)
    const int s = (lo >> 1) & 3;   // write-rotation amount (bank spread)
    const float* xb = x + (size_t)b * Dv * Nv + n0;
#pragma unroll
    for (int r = 0; r < 8; r++) {
      int d = (hi + 32 * r) * 2;        // even d row; covers 0..510
      int n4 = lo * 4;
      float4 v0 = *(const float4*)&xb[(size_t)d * Nv + n4];
      float4 v1 = *(const float4*)&xb[(size_t)(d + 1) * Nv + n4];
      // LDS xT: dword at [n][d] = (x[d][n], x[d+1][n]); d even -> aligned
      unsigned w0 = pack2(v0.x, v1.x);
      unsigned w1 = pack2(v0.y, v1.y);
      unsigned w2 = pack2(v0.z, v1.z);
      unsigned w3 = pack2(v0.w, v1.w);
      // rotate data+row-offset by s: instruction j writes row n4+((j+s)&3)
      unsigned a0 = (s & 1) ? w1 : w0, a1 = (s & 1) ? w2 : w1,
               a2 = (s & 1) ? w3 : w2, a3 = (s & 1) ? w0 : w3;
      unsigned b0 = (s & 2) ? a2 : a0, b1 = (s & 2) ? a3 : a1,
               b2 = (s & 2) ? a0 : a2, b3 = (s & 2) ? a1 : a3;
      *(unsigned*)&xT[(n4 + ((0 + s) & 3)) * 520 + d] = b0;
      *(unsigned*)&xT[(n4 + ((1 + s) & 3)) * 520 + d] = b1;
      *(unsigned*)&xT[(n4 + ((2 + s) & 3)) * 520 + d] = b2;
      *(unsigned*)&xT[(n4 + ((3 + s) & 3)) * 520 + d] = b3;
    }
  }
  __syncthreads();

  // ---------------- scores GEMM ----------------
  const int wv = t >> 6;        // 0..7
  const int lane = t & 63;
  const int q = lane >> 4;
  const int m = lane & 15;
  const int k16 = wv & 3;       // k-tile
  const int nsub = wv >> 2;     // n-half: cols [nsub*32, +32)

  f32x4 acc0 = {0.f, 0.f, 0.f, 0.f};
  f32x4 acc1 = {0.f, 0.f, 0.f, 0.f};

  const unsigned short* wp = wbf + (size_t)(k16 * 16 + m) * Dv + q * 8;
  const unsigned short* l0 = &xT[(nsub * 32 + m) * 520 + q * 8];
  const unsigned short* l1 = l0 + 16 * 520;

#pragma unroll
  for (int d0 = 0; d0 < Dv; d0 += 32) {
    bf16x8 af = *(const bf16x8*)(wp + d0);
    bf16x8 bf0 = *(const bf16x8*)(l0 + d0);
    bf16x8 bf1 = *(const bf16x8*)(l1 + d0);
    acc0 = __builtin_amdgcn_mfma_f32_16x16x32_bf16(af, bf0, acc0, 0, 0, 0);
    acc1 = __builtin_amdgcn_mfma_f32_16x16x32_bf16(af, bf1, acc1, 0, 0, 0);
  }

  // ---------------- softmax over k (64) ----------------
  float m0 = fmaxf(fmaxf(acc0[0], acc0[1]), fmaxf(acc0[2], acc0[3]));
  float m1 = fmaxf(fmaxf(acc1[0], acc1[1]), fmaxf(acc1[2], acc1[3]));
  m0 = fmaxf(m0, __shfl_xor(m0, 16)); m0 = fmaxf(m0, __shfl_xor(m0, 32));
  m1 = fmaxf(m1, __shfl_xor(m1, 16)); m1 = fmaxf(m1, __shfl_xor(m1, 32));
  if (q == 0) {
    redmax[k16][nsub * 32 + m] = m0;
    redmax[k16][nsub * 32 + 16 + m] = m1;
  }
  __syncthreads();
  const int c0 = nsub * 32 + m, c1 = c0 + 16;
  float mc0 = fmaxf(fmaxf(redmax[0][c0], redmax[1][c0]), fmaxf(redmax[2][c0], redmax[3][c0]));
  float mc1 = fmaxf(fmaxf(redmax[0][c1], redmax[1][c1]), fmaxf(redmax[2][c1], redmax[3][c1]));

  float e0[4], e1[4];
  float s0 = 0.f, s1 = 0.f;
#pragma unroll
  for (int r = 0; r < 4; r++) {
    e0[r] = __expf(acc0[r] - mc0); s0 += e0[r];
    e1[r] = __expf(acc1[r] - mc1); s1 += e1[r];
  }
  s0 += __shfl_xor(s0, 16); s0 += __shfl_xor(s0, 32);
  s1 += __shfl_xor(s1, 16); s1 += __shfl_xor(s1, 32);
  if (q == 0) {
    redsum[k16][c0] = s0;
    redsum[k16][c1] = s1;
  }
  __syncthreads();
  float sc0 = 1.0f / (redsum[0][c0] + redsum[1][c0] + redsum[2][c0] + redsum[3][c0]);
  float sc1 = 1.0f / (redsum[0][c1] + redsum[1][c1] + redsum[2][c1] + redsum[3][c1]);

  // ---------------- assign write + asum ----------------
  unsigned short* ab = assign + ((size_t)b * Kv + k16 * 16 + q * 4) * Nv + n0 + nsub * 32;
#pragma unroll
  for (int r = 0; r < 4; r++) {
    float v0 = e0[r] * sc0;
    float v1 = e1[r] * sc1;
    ab[(size_t)r * Nv + m] = f2b(v0);
    ab[(size_t)r * Nv + 16 + m] = f2b(v1);
    float p = v0 + v1;
    p += __shfl_xor(p, 1); p += __shfl_xor(p, 2);
    p += __shfl_xor(p, 4); p += __shfl_xor(p, 8);
    if (m == 0) atomicAdd(&asum[b * Kv + k16 * 16 + q * 4 + r], p);
  }
}

// ---------------------------------------------------------------------------
// Kernel 2 (R7): vlad[b,d,k] = sum_n x*assign - centers*asum via bf16 MFMA.
// Keeps R6's dataflow (fp32 x from L3, no xbf round-trip) but RESTORES the
// R5 pipeline: 512 thr / 8 waves = (ksub 0..3) x (nh 0..1), each wave does
// an n-half (512) with an explicit depth-8 register prefetch:
//   prologue: issue loads for i=0..7 (x as float4 pairs, assign as bf16x8)
//   steady:   pack xf[i]->bf16, MFMA, then issue loads for i+8
// ~96 live VGPRs of prefetch state; __launch_bounds__(512,4) caps at 128.
// Cross-wave nh reduction via sred LDS. Fuses colsq via atomics.
// Grid (D/16, B) = (32, 32).
// ---------------------------------------------------------------------------
__global__ __launch_bounds__(512, 4) void vlad_mfma(
    const float* __restrict__ x, const unsigned short* __restrict__ assign,
    const float* __restrict__ centers, const float* __restrict__ asum,
    float* __restrict__ vlad, float* __restrict__ colsq) {
  __shared__ float sred[4][64][4];   // [ksub][lane][r] from nh==1 waves

  const int t = threadIdx.x;
  const int b = blockIdx.y;
  const int d0 = blockIdx.x * 16;
  const int wv = t >> 6;
  const int ksub = wv & 3;
  const int nh = wv >> 2;            // n-half
  const int lane = t & 63;
  const int q = lane >> 4;
  const int m = lane & 15;
  const int k16 = ksub * 16;

  const float* xp = x + ((size_t)b * Dv + d0 + m) * Nv + nh * 512 + q * 8;
  const unsigned short* ap = assign + ((size_t)b * Kv + k16 + m) * Nv + nh * 512 + q * 8;

  f32x4 acc = {0.f, 0.f, 0.f, 0.f};
  float4 xf[8][2];
  bf16x8 av[8];
#pragma unroll
  for (int i = 0; i < 8; i++) {
    xf[i][0] = *(const float4*)(xp + i * 32);
    xf[i][1] = *(const float4*)(xp + i * 32 + 4);
    av[i] = *(const bf16x8*)(ap + i * 32);
  }
#pragma unroll
  for (int i = 0; i < 8; i++) {
    bf16x8 xv;
    unsigned* xu = (unsigned*)&xv;
    xu[0] = pack2(xf[i][0].x, xf[i][0].y);
    xu[1] = pack2(xf[i][0].z, xf[i][0].w);
    xu[2] = pack2(xf[i][1].x, xf[i][1].y);
    xu[3] = pack2(xf[i][1].z, xf[i][1].w);
    acc = __builtin_amdgcn_mfma_f32_16x16x32_bf16(xv, av[i], acc, 0, 0, 0);
    xf[i][0] = *(const float4*)(xp + 256 + i * 32);
    xf[i][1] = *(const float4*)(xp + 256 + i * 32 + 4);
    av[i] = *(const bf16x8*)(ap + 256 + i * 32);
  }
#pragma unroll
  for (int i = 0; i < 8; i++) {
    bf16x8 xv;
    unsigned* xu = (unsigned*)&xv;
    xu[0] = pack2(xf[i][0].x, xf[i][0].y);
    xu[1] = pack2(xf[i][0].z, xf[i][0].w);
    xu[2] = pack2(xf[i][1].x, xf[i][1].y);
    xu[3] = pack2(xf[i][1].z, xf[i][1].w);
    acc = __builtin_amdgcn_mfma_f32_16x16x32_bf16(xv, av[i], acc, 0, 0, 0);
  }

  if (nh == 1) {
#pragma unroll
    for (int r = 0; r < 4; r++) sred[ksub][lane][r] = acc[r];
  }
  __syncthreads();
  if (nh == 0) {
    const int k = k16 + m;
    const float as = asum[b * Kv + k];
    float ss = 0.f;
#pragma unroll
    for (int r = 0; r < 4; r++) {
      float v = acc[r] + sred[ksub][lane][r];
      int d = d0 + q * 4 + r;
      float val = v - centers[d * Kv + k] * as;
      vlad[((size_t)b * Dv + d) * Kv + k] = val;
      ss = fmaf(val, val, ss);
    }
    ss += __shfl_xor(ss, 16);
    ss += __shfl_xor(ss, 32);
    if (q == 0) atomicAdd(&colsq[b * Kv + k], ss);
  }
}

// ---------------------------------------------------------------------------
// Kernel D: out = vlad * colscale[b,k] * bscale[b]; scales from colsq
// in-block. Grid 4096 x 256.
// ---------------------------------------------------------------------------
__global__ __launch_bounds__(256) void scale_kernel(
    const float* __restrict__ vlad, const float* __restrict__ colsq,
    float* __restrict__ out) {
  const int t = threadIdx.x;
  const size_t i = (size_t)blockIdx.x * 256 + t;
  const int b = (int)(i >> 15);  // D*K = 32768 per b
  __shared__ float scs[64];
  __shared__ float bsh;
  if (t < 64) {
    float tot = colsq[b * Kv + t];
    float sc = 1.0f / fmaxf(sqrtf(tot), EPSv);
    scs[t] = sc;
    float contrib = tot * sc * sc;
#pragma unroll
    for (int off = 32; off > 0; off >>= 1) contrib += __shfl_down(contrib, off);
    if (t == 0) bsh = 1.0f / fmaxf(sqrtf(contrib), EPSv);
  }
  __syncthreads();
  out[i] = vlad[i] * scs[i & 63] * bsh;
}

extern "C" void kernel_launch(void* const* d_in, const int* in_sizes, int n_in,
                              void* d_out, int out_size, void* d_ws, size_t ws_size,
                              hipStream_t stream) {
  const float* x = (const float*)d_in[0];        // [B, D, N]
  const float* w = (const float*)d_in[1];        // [K, D]
  const float* centers = (const float*)d_in[2];  // [D, K]
  float* out = (float*)d_out;                    // [B, D*K]

  char* ws = (char*)d_ws;
  unsigned short* assign = (unsigned short*)ws;               // [B][K][N] bf16, 4 MB
  float* vlad = (float*)(ws + 4194304);                       // [B][D][K] fp32, 4 MB
  unsigned short* wbf = (unsigned short*)(ws + 8388608);      // [K][D] bf16, 64 KB
  float* asum = (float*)(ws + 8454144);                       // B*K
  float* colsq = asum + Bv * Kv;                              // B*K (contiguous)

  hipMemsetAsync(asum, 0, (size_t)2 * Bv * Kv * sizeof(float), stream);

  wconv<<<32, 256, 0, stream>>>(w, wbf);
  fused_scores<<<dim3(Nv / 64, Bv), 512, 0, stream>>>(x, wbf, assign, asum);
  vlad_mfma<<<dim3(Dv / 16, Bv), 512, 0, stream>>>(x, assign, centers, asum, vlad, colsq);
  scale_kernel<<<(Bv * Dv * Kv) / 256, 256, 0, stream>>>(vlad, colsq, out);
}

// Round 3
// 154.273 us; speedup vs baseline: 1.0069x; 1.0069x over previous
//
#include <hip/hip_runtime.h>
#include <hip/hip_bf16.h>

#define Bv 32
#define Dv 512
#define Kv 64
#define Nv 1024
#define EPSv 1e-12f

typedef __attribute__((ext_vector_type(8))) short bf16x8;
typedef __attribute__((ext_vector_type(4))) float f32x4;

// fp32 -> bf16 (RNE), bit-level
__device__ __forceinline__ unsigned short f2b(float f) {
  union { float f; unsigned u; } v; v.f = f;
  unsigned r = v.u + 0x7fffu + ((v.u >> 16) & 1u);
  return (unsigned short)(r >> 16);
}
__device__ __forceinline__ unsigned pack2(float a, float b) {
  return (unsigned)f2b(a) | ((unsigned)f2b(b) << 16);
}

// ---------------------------------------------------------------------------
// Kernel W: convert conv_w (K x D fp32) -> bf16. 32 blocks x 256 thr.
// ---------------------------------------------------------------------------
__global__ __launch_bounds__(256) void wconv(const float* __restrict__ w,
                                             unsigned short* __restrict__ wbf) {
  int i = (blockIdx.x * 256 + threadIdx.x) * 4;
  float4 v = *(const float4*)&w[i];
  uint2 o = make_uint2(pack2(v.x, v.y), pack2(v.z, v.w));
  *(uint2*)&wbf[i] = o;
}

// ---------------------------------------------------------------------------
// Kernel 1 (fused T+A), unchanged:
//  - NO xbf writeback (vlad kernel re-reads fp32 x from L3 instead)
//  - staging LDS writes rotated by s=(lo>>1)&3 to break the 8-way bank
//    conflict
// Grid (N/64, B) = (16, 32) = 512 blocks, 512 threads (8 waves).
// ---------------------------------------------------------------------------
__global__ __launch_bounds__(512) void fused_scores(
    const float* __restrict__ x, const unsigned short* __restrict__ wbf,
    unsigned short* __restrict__ assign, float* __restrict__ asum) {
  __shared__ unsigned short xT[64 * 520];   // [n][d], pitch 520 shorts (1040B)
  __shared__ float redmax[4][64];
  __shared__ float redsum[4][64];

  const int t = threadIdx.x;   // 0..511
  const int b = blockIdx.y;
  const int n0 = blockIdx.x * 64;

  // ---------------- staging ----------------
  {
    const int lo = t & 15;     // n-quad
    const int hi = t >> 4;     // 0..31 (d-pair subindex)
    const int s = (lo >> 1) & 3;   // write-rotation amount (bank spread)
    const float* xb = x + (size_t)b * Dv * Nv + n0;
#pragma unroll
    for (int r = 0; r < 8; r++) {
      int d = (hi + 32 * r) * 2;        // even d row; covers 0..510
      int n4 = lo * 4;
      float4 v0 = *(const float4*)&xb[(size_t)d * Nv + n4];
      float4 v1 = *(const float4*)&xb[(size_t)(d + 1) * Nv + n4];
      // LDS xT: dword at [n][d] = (x[d][n], x[d+1][n]); d even -> aligned
      unsigned w0 = pack2(v0.x, v1.x);
      unsigned w1 = pack2(v0.y, v1.y);
      unsigned w2 = pack2(v0.z, v1.z);
      unsigned w3 = pack2(v0.w, v1.w);
      // rotate data+row-offset by s: instruction j writes row n4+((j+s)&3)
      unsigned a0 = (s & 1) ? w1 : w0, a1 = (s & 1) ? w2 : w1,
               a2 = (s & 1) ? w3 : w2, a3 = (s & 1) ? w0 : w3;
      unsigned b0 = (s & 2) ? a2 : a0, b1 = (s & 2) ? a3 : a1,
               b2 = (s & 2) ? a0 : a2, b3 = (s & 2) ? a1 : a3;
      *(unsigned*)&xT[(n4 + ((0 + s) & 3)) * 520 + d] = b0;
      *(unsigned*)&xT[(n4 + ((1 + s) & 3)) * 520 + d] = b1;
      *(unsigned*)&xT[(n4 + ((2 + s) & 3)) * 520 + d] = b2;
      *(unsigned*)&xT[(n4 + ((3 + s) & 3)) * 520 + d] = b3;
    }
  }
  __syncthreads();

  // ---------------- scores GEMM ----------------
  const int wv = t >> 6;        // 0..7
  const int lane = t & 63;
  const int q = lane >> 4;
  const int m = lane & 15;
  const int k16 = wv & 3;       // k-tile
  const int nsub = wv >> 2;     // n-half: cols [nsub*32, +32)

  f32x4 acc0 = {0.f, 0.f, 0.f, 0.f};
  f32x4 acc1 = {0.f, 0.f, 0.f, 0.f};

  const unsigned short* wp = wbf + (size_t)(k16 * 16 + m) * Dv + q * 8;
  const unsigned short* l0 = &xT[(nsub * 32 + m) * 520 + q * 8];
  const unsigned short* l1 = l0 + 16 * 520;

#pragma unroll
  for (int d0 = 0; d0 < Dv; d0 += 32) {
    bf16x8 af = *(const bf16x8*)(wp + d0);
    bf16x8 bf0 = *(const bf16x8*)(l0 + d0);
    bf16x8 bf1 = *(const bf16x8*)(l1 + d0);
    acc0 = __builtin_amdgcn_mfma_f32_16x16x32_bf16(af, bf0, acc0, 0, 0, 0);
    acc1 = __builtin_amdgcn_mfma_f32_16x16x32_bf16(af, bf1, acc1, 0, 0, 0);
  }

  // ---------------- softmax over k (64) ----------------
  float m0 = fmaxf(fmaxf(acc0[0], acc0[1]), fmaxf(acc0[2], acc0[3]));
  float m1 = fmaxf(fmaxf(acc1[0], acc1[1]), fmaxf(acc1[2], acc1[3]));
  m0 = fmaxf(m0, __shfl_xor(m0, 16)); m0 = fmaxf(m0, __shfl_xor(m0, 32));
  m1 = fmaxf(m1, __shfl_xor(m1, 16)); m1 = fmaxf(m1, __shfl_xor(m1, 32));
  if (q == 0) {
    redmax[k16][nsub * 32 + m] = m0;
    redmax[k16][nsub * 32 + 16 + m] = m1;
  }
  __syncthreads();
  const int c0 = nsub * 32 + m, c1 = c0 + 16;
  float mc0 = fmaxf(fmaxf(redmax[0][c0], redmax[1][c0]), fmaxf(redmax[2][c0], redmax[3][c0]));
  float mc1 = fmaxf(fmaxf(redmax[0][c1], redmax[1][c1]), fmaxf(redmax[2][c1], redmax[3][c1]));

  float e0[4], e1[4];
  float s0 = 0.f, s1 = 0.f;
#pragma unroll
  for (int r = 0; r < 4; r++) {
    e0[r] = __expf(acc0[r] - mc0); s0 += e0[r];
    e1[r] = __expf(acc1[r] - mc1); s1 += e1[r];
  }
  s0 += __shfl_xor(s0, 16); s0 += __shfl_xor(s0, 32);
  s1 += __shfl_xor(s1, 16); s1 += __shfl_xor(s1, 32);
  if (q == 0) {
    redsum[k16][c0] = s0;
    redsum[k16][c1] = s1;
  }
  __syncthreads();
  float sc0 = 1.0f / (redsum[0][c0] + redsum[1][c0] + redsum[2][c0] + redsum[3][c0]);
  float sc1 = 1.0f / (redsum[0][c1] + redsum[1][c1] + redsum[2][c1] + redsum[3][c1]);

  // ---------------- assign write + asum ----------------
  unsigned short* ab = assign + ((size_t)b * Kv + k16 * 16 + q * 4) * Nv + n0 + nsub * 32;
#pragma unroll
  for (int r = 0; r < 4; r++) {
    float v0 = e0[r] * sc0;
    float v1 = e1[r] * sc1;
    ab[(size_t)r * Nv + m] = f2b(v0);
    ab[(size_t)r * Nv + 16 + m] = f2b(v1);
    float p = v0 + v1;
    p += __shfl_xor(p, 1); p += __shfl_xor(p, 2);
    p += __shfl_xor(p, 4); p += __shfl_xor(p, 8);
    if (m == 0) atomicAdd(&asum[b * Kv + k16 * 16 + q * 4 + r], p);
  }
}

// ---------------------------------------------------------------------------
// Kernel 2 (R8): vlad[b,d,k] = sum_n x*assign - centers*asum via bf16 MFMA.
// R7's depth-8 register prefetch was silently DESTROYED by the scheduler
// (VGPR_Count=32 proves loads were re-sunk to their uses). R8 pins it with
// __builtin_amdgcn_sched_barrier(0):
//   prologue: issue all 8 load groups, SBAR
//   steady:   {pack+MFMA group i; issue loads group i+8; SBAR} x8
//   drain:    pack+MFMA groups 8..15
// -> waitcnt before each pack is a counted vmcnt(~21), never 0; ~21 loads
// in flight per wave. __launch_bounds__(512,2) lifts VGPR cap to 256 so the
// ~110-reg ring is not squeezed back out (expect VGPR ~110-130).
// Grid (D/16, B) = (32, 32), 512 thr / 8 waves = (ksub 0..3) x (nh 0..1).
// ---------------------------------------------------------------------------
__global__ __launch_bounds__(512, 2) void vlad_mfma(
    const float* __restrict__ x, const unsigned short* __restrict__ assign,
    const float* __restrict__ centers, const float* __restrict__ asum,
    float* __restrict__ vlad, float* __restrict__ colsq) {
  __shared__ float sred[4][64][4];   // [ksub][lane][r] from nh==1 waves

  const int t = threadIdx.x;
  const int b = blockIdx.y;
  const int d0 = blockIdx.x * 16;
  const int wv = t >> 6;
  const int ksub = wv & 3;
  const int nh = wv >> 2;            // n-half
  const int lane = t & 63;
  const int q = lane >> 4;
  const int m = lane & 15;
  const int k16 = ksub * 16;

  const float* xp = x + ((size_t)b * Dv + d0 + m) * Nv + nh * 512 + q * 8;
  const unsigned short* ap = assign + ((size_t)b * Kv + k16 + m) * Nv + nh * 512 + q * 8;

  f32x4 acc = {0.f, 0.f, 0.f, 0.f};
  float4 xf0[8], xf1[8];
  bf16x8 av[8];

  // prologue: 24 loads in flight
#pragma unroll
  for (int i = 0; i < 8; i++) {
    xf0[i] = *(const float4*)(xp + i * 32);
    xf1[i] = *(const float4*)(xp + i * 32 + 4);
    av[i] = *(const bf16x8*)(ap + i * 32);
  }
  __builtin_amdgcn_sched_barrier(0);

  // steady state: consume group i, refill slot i with group i+8
#pragma unroll
  for (int i = 0; i < 8; i++) {
    bf16x8 xv;
    unsigned* xu = (unsigned*)&xv;
    xu[0] = pack2(xf0[i].x, xf0[i].y);
    xu[1] = pack2(xf0[i].z, xf0[i].w);
    xu[2] = pack2(xf1[i].x, xf1[i].y);
    xu[3] = pack2(xf1[i].z, xf1[i].w);
    acc = __builtin_amdgcn_mfma_f32_16x16x32_bf16(xv, av[i], acc, 0, 0, 0);
    xf0[i] = *(const float4*)(xp + 256 + i * 32);
    xf1[i] = *(const float4*)(xp + 256 + i * 32 + 4);
    av[i] = *(const bf16x8*)(ap + 256 + i * 32);
    __builtin_amdgcn_sched_barrier(0);
  }

  // drain
#pragma unroll
  for (int i = 0; i < 8; i++) {
    bf16x8 xv;
    unsigned* xu = (unsigned*)&xv;
    xu[0] = pack2(xf0[i].x, xf0[i].y);
    xu[1] = pack2(xf0[i].z, xf0[i].w);
    xu[2] = pack2(xf1[i].x, xf1[i].y);
    xu[3] = pack2(xf1[i].z, xf1[i].w);
    acc = __builtin_amdgcn_mfma_f32_16x16x32_bf16(xv, av[i], acc, 0, 0, 0);
  }

  if (nh == 1) {
#pragma unroll
    for (int r = 0; r < 4; r++) sred[ksub][lane][r] = acc[r];
  }
  __syncthreads();
  if (nh == 0) {
    const int k = k16 + m;
    const float as = asum[b * Kv + k];
    float ss = 0.f;
#pragma unroll
    for (int r = 0; r < 4; r++) {
      float v = acc[r] + sred[ksub][lane][r];
      int d = d0 + q * 4 + r;
      float val = v - centers[d * Kv + k] * as;
      vlad[((size_t)b * Dv + d) * Kv + k] = val;
      ss = fmaf(val, val, ss);
    }
    ss += __shfl_xor(ss, 16);
    ss += __shfl_xor(ss, 32);
    if (q == 0) atomicAdd(&colsq[b * Kv + k], ss);
  }
}

// ---------------------------------------------------------------------------
// Kernel D: out = vlad * colscale[b,k] * bscale[b]; scales from colsq
// in-block. Grid 4096 x 256.
// ---------------------------------------------------------------------------
__global__ __launch_bounds__(256) void scale_kernel(
    const float* __restrict__ vlad, const float* __restrict__ colsq,
    float* __restrict__ out) {
  const int t = threadIdx.x;
  const size_t i = (size_t)blockIdx.x * 256 + t;
  const int b = (int)(i >> 15);  // D*K = 32768 per b
  __shared__ float scs[64];
  __shared__ float bsh;
  if (t < 64) {
    float tot = colsq[b * Kv + t];
    float sc = 1.0f / fmaxf(sqrtf(tot), EPSv);
    scs[t] = sc;
    float contrib = tot * sc * sc;
#pragma unroll
    for (int off = 32; off > 0; off >>= 1) contrib += __shfl_down(contrib, off);
    if (t == 0) bsh = 1.0f / fmaxf(sqrtf(contrib), EPSv);
  }
  __syncthreads();
  out[i] = vlad[i] * scs[i & 63] * bsh;
}

extern "C" void kernel_launch(void* const* d_in, const int* in_sizes, int n_in,
                              void* d_out, int out_size, void* d_ws, size_t ws_size,
                              hipStream_t stream) {
  const float* x = (const float*)d_in[0];        // [B, D, N]
  const float* w = (const float*)d_in[1];        // [K, D]
  const float* centers = (const float*)d_in[2];  // [D, K]
  float* out = (float*)d_out;                    // [B, D*K]

  char* ws = (char*)d_ws;
  unsigned short* assign = (unsigned short*)ws;               // [B][K][N] bf16, 4 MB
  float* vlad = (float*)(ws + 4194304);                       // [B][D][K] fp32, 4 MB
  unsigned short* wbf = (unsigned short*)(ws + 8388608);      // [K][D] bf16, 64 KB
  float* asum = (float*)(ws + 8454144);                       // B*K
  float* colsq = asum + Bv * Kv;                              // B*K (contiguous)

  hipMemsetAsync(asum, 0, (size_t)2 * Bv * Kv * sizeof(float), stream);

  wconv<<<32, 256, 0, stream>>>(w, wbf);
  fused_scores<<<dim3(Nv / 64, Bv), 512, 0, stream>>>(x, wbf, assign, asum);
  vlad_mfma<<<dim3(Dv / 16, Bv), 512, 0, stream>>>(x, assign, centers, asum, vlad, colsq);
  scale_kernel<<<(Bv * Dv * Kv) / 256, 256, 0, stream>>>(vlad, colsq, out);
}

// Round 4
// 145.257 us; speedup vs baseline: 1.0693x; 1.0621x over previous
//
#include <hip/hip_runtime.h>
#include <hip/hip_bf16.h>

#define Bv 32
#define Dv 512
#define Kv 64
#define Nv 1024
#define EPSv 1e-12f

typedef __attribute__((ext_vector_type(8))) short bf16x8;
typedef __attribute__((ext_vector_type(4))) float f32x4;

// fp32 -> bf16 (RNE), bit-level
__device__ __forceinline__ unsigned short f2b(float f) {
  union { float f; unsigned u; } v; v.f = f;
  unsigned r = v.u + 0x7fffu + ((v.u >> 16) & 1u);
  return (unsigned short)(r >> 16);
}
__device__ __forceinline__ unsigned pack2(float a, float b) {
  return (unsigned)f2b(a) | ((unsigned)f2b(b) << 16);
}

// ---------------------------------------------------------------------------
// Kernel W: convert conv_w (K x D fp32) -> bf16. 32 blocks x 256 thr.
// ---------------------------------------------------------------------------
__global__ __launch_bounds__(256) void wconv(const float* __restrict__ w,
                                             unsigned short* __restrict__ wbf) {
  int i = (blockIdx.x * 256 + threadIdx.x) * 4;
  float4 v = *(const float4*)&w[i];
  uint2 o = make_uint2(pack2(v.x, v.y), pack2(v.z, v.w));
  *(uint2*)&wbf[i] = o;
}

// ---------------------------------------------------------------------------
// Kernel 1 (fused T+A), R9:
//  - restores the xbf writeback (R5's fast-vlad regime: vlad reads bf16 data
//    that was WRITTEN by the previous kernel -> L2/L3-warm) but in a TILED
//    layout: each block's 512d x 64n tile is one contiguous 64KB region
//    xbf[(b*16+ntile)*32768 + d*64 + nloc]. Writes are dense 1KB windows
//    per wave-iteration instead of R5's 2KB-strided 8B runs (27us -> ~6us).
//  - assign likewise tiled: [(b*16+ntile)*4096 + k*64 + nloc], 8KB/block.
//  - staging LDS rotation (bank-conflict fix) kept.
// Grid (N/64, B) = (16, 32) = 512 blocks, 512 threads (8 waves).
// ---------------------------------------------------------------------------
__global__ __launch_bounds__(512) void fused_scores(
    const float* __restrict__ x, const unsigned short* __restrict__ wbf,
    unsigned short* __restrict__ xbf, unsigned short* __restrict__ assign,
    float* __restrict__ asum) {
  __shared__ unsigned short xT[64 * 520];   // [n][d], pitch 520 shorts (1040B)
  __shared__ float redmax[4][64];
  __shared__ float redsum[4][64];

  const int t = threadIdx.x;   // 0..511
  const int b = blockIdx.y;
  const int nt = blockIdx.x;
  const int n0 = nt * 64;

  // ---------------- staging (+ tiled xbf writeback) ----------------
  {
    const int lo = t & 15;     // n-quad
    const int hi = t >> 4;     // 0..31 (d-pair subindex)
    const int s = (lo >> 1) & 3;   // write-rotation amount (bank spread)
    const float* xb = x + (size_t)b * Dv * Nv + n0;
    unsigned short* xt = xbf + ((size_t)b * 16 + nt) * (Dv * 64);
#pragma unroll
    for (int r = 0; r < 8; r++) {
      int d = (hi + 32 * r) * 2;        // even d row; covers 0..510
      int n4 = lo * 4;
      float4 v0 = *(const float4*)&xb[(size_t)d * Nv + n4];
      float4 v1 = *(const float4*)&xb[(size_t)(d + 1) * Nv + n4];
      // tiled xbf write: row-major within 64KB tile, dense windows
      *(uint2*)&xt[(size_t)d * 64 + n4] =
          make_uint2(pack2(v0.x, v0.y), pack2(v0.z, v0.w));
      *(uint2*)&xt[(size_t)(d + 1) * 64 + n4] =
          make_uint2(pack2(v1.x, v1.y), pack2(v1.z, v1.w));
      // LDS xT: dword at [n][d] = (x[d][n], x[d+1][n]); d even -> aligned
      unsigned w0 = pack2(v0.x, v1.x);
      unsigned w1 = pack2(v0.y, v1.y);
      unsigned w2 = pack2(v0.z, v1.z);
      unsigned w3 = pack2(v0.w, v1.w);
      // rotate data+row-offset by s: instruction j writes row n4+((j+s)&3)
      unsigned a0 = (s & 1) ? w1 : w0, a1 = (s & 1) ? w2 : w1,
               a2 = (s & 1) ? w3 : w2, a3 = (s & 1) ? w0 : w3;
      unsigned b0 = (s & 2) ? a2 : a0, b1 = (s & 2) ? a3 : a1,
               b2 = (s & 2) ? a0 : a2, b3 = (s & 2) ? a1 : a3;
      *(unsigned*)&xT[(n4 + ((0 + s) & 3)) * 520 + d] = b0;
      *(unsigned*)&xT[(n4 + ((1 + s) & 3)) * 520 + d] = b1;
      *(unsigned*)&xT[(n4 + ((2 + s) & 3)) * 520 + d] = b2;
      *(unsigned*)&xT[(n4 + ((3 + s) & 3)) * 520 + d] = b3;
    }
  }
  __syncthreads();

  // ---------------- scores GEMM ----------------
  const int wv = t >> 6;        // 0..7
  const int lane = t & 63;
  const int q = lane >> 4;
  const int m = lane & 15;
  const int k16 = wv & 3;       // k-tile
  const int nsub = wv >> 2;     // n-half: cols [nsub*32, +32)

  f32x4 acc0 = {0.f, 0.f, 0.f, 0.f};
  f32x4 acc1 = {0.f, 0.f, 0.f, 0.f};

  const unsigned short* wp = wbf + (size_t)(k16 * 16 + m) * Dv + q * 8;
  const unsigned short* l0 = &xT[(nsub * 32 + m) * 520 + q * 8];
  const unsigned short* l1 = l0 + 16 * 520;

#pragma unroll
  for (int d0 = 0; d0 < Dv; d0 += 32) {
    bf16x8 af = *(const bf16x8*)(wp + d0);
    bf16x8 bf0 = *(const bf16x8*)(l0 + d0);
    bf16x8 bf1 = *(const bf16x8*)(l1 + d0);
    acc0 = __builtin_amdgcn_mfma_f32_16x16x32_bf16(af, bf0, acc0, 0, 0, 0);
    acc1 = __builtin_amdgcn_mfma_f32_16x16x32_bf16(af, bf1, acc1, 0, 0, 0);
  }

  // ---------------- softmax over k (64) ----------------
  float m0 = fmaxf(fmaxf(acc0[0], acc0[1]), fmaxf(acc0[2], acc0[3]));
  float m1 = fmaxf(fmaxf(acc1[0], acc1[1]), fmaxf(acc1[2], acc1[3]));
  m0 = fmaxf(m0, __shfl_xor(m0, 16)); m0 = fmaxf(m0, __shfl_xor(m0, 32));
  m1 = fmaxf(m1, __shfl_xor(m1, 16)); m1 = fmaxf(m1, __shfl_xor(m1, 32));
  if (q == 0) {
    redmax[k16][nsub * 32 + m] = m0;
    redmax[k16][nsub * 32 + 16 + m] = m1;
  }
  __syncthreads();
  const int c0 = nsub * 32 + m, c1 = c0 + 16;
  float mc0 = fmaxf(fmaxf(redmax[0][c0], redmax[1][c0]), fmaxf(redmax[2][c0], redmax[3][c0]));
  float mc1 = fmaxf(fmaxf(redmax[0][c1], redmax[1][c1]), fmaxf(redmax[2][c1], redmax[3][c1]));

  float e0[4], e1[4];
  float s0 = 0.f, s1 = 0.f;
#pragma unroll
  for (int r = 0; r < 4; r++) {
    e0[r] = __expf(acc0[r] - mc0); s0 += e0[r];
    e1[r] = __expf(acc1[r] - mc1); s1 += e1[r];
  }
  s0 += __shfl_xor(s0, 16); s0 += __shfl_xor(s0, 32);
  s1 += __shfl_xor(s1, 16); s1 += __shfl_xor(s1, 32);
  if (q == 0) {
    redsum[k16][c0] = s0;
    redsum[k16][c1] = s1;
  }
  __syncthreads();
  float sc0 = 1.0f / (redsum[0][c0] + redsum[1][c0] + redsum[2][c0] + redsum[3][c0]);
  float sc1 = 1.0f / (redsum[0][c1] + redsum[1][c1] + redsum[2][c1] + redsum[3][c1]);

  // ---------------- assign write (tiled) + asum ----------------
  unsigned short* at_ = assign + ((size_t)b * 16 + nt) * (Kv * 64)
                        + (size_t)(k16 * 16 + q * 4) * 64 + nsub * 32;
#pragma unroll
  for (int r = 0; r < 4; r++) {
    float v0 = e0[r] * sc0;
    float v1 = e1[r] * sc1;
    at_[r * 64 + m] = f2b(v0);
    at_[r * 64 + 16 + m] = f2b(v1);
    float p = v0 + v1;
    p += __shfl_xor(p, 1); p += __shfl_xor(p, 2);
    p += __shfl_xor(p, 4); p += __shfl_xor(p, 8);
    if (m == 0) atomicAdd(&asum[b * Kv + k16 * 16 + q * 4 + r], p);
  }
}

// ---------------------------------------------------------------------------
// Kernel 2 (R9): vlad[b,d,k] = sum_n xbf*assign - centers*asum, bf16 MFMA.
// Both operands read from TILED bf16 buffers freshly written by kernel 1
// (L2/L3-warm -> short latency; R5 empirically proved this regime ~8us).
// A wave's fragment load is one dense 2KB window (16 rows x 128B adjacent).
// No fp32->bf16 pack needed. Depth-8 register prefetch + sched_barrier kept.
// Grid (D/16, B) = (32, 32), 512 thr / 8 waves = (ksub 0..3) x (nh 0..1);
// each nh-half covers 8 tiles x 2 chunks = 16 MFMA groups.
// ---------------------------------------------------------------------------
__global__ __launch_bounds__(512, 2) void vlad_mfma(
    const unsigned short* __restrict__ xbf, const unsigned short* __restrict__ assign,
    const float* __restrict__ centers, const float* __restrict__ asum,
    float* __restrict__ vlad, float* __restrict__ colsq) {
  __shared__ float sred[4][64][4];   // [ksub][lane][r] from nh==1 waves

  const int t = threadIdx.x;
  const int b = blockIdx.y;
  const int d0 = blockIdx.x * 16;
  const int wv = t >> 6;
  const int ksub = wv & 3;
  const int nh = wv >> 2;            // n-half: tiles nh*8 .. nh*8+7
  const int lane = t & 63;
  const int q = lane >> 4;
  const int m = lane & 15;
  const int k16 = ksub * 16;

  // group g (0..15): tile = g>>1, chunk = g&1
  const unsigned short* xp = xbf + ((size_t)b * 16 + nh * 8) * (Dv * 64)
                             + (size_t)(d0 + m) * 64 + q * 8;
  const unsigned short* ap = assign + ((size_t)b * 16 + nh * 8) * (Kv * 64)
                             + (size_t)(k16 + m) * 64 + q * 8;

  f32x4 acc = {0.f, 0.f, 0.f, 0.f};
  bf16x8 xv[8], av[8];

  // prologue: 16 loads in flight (groups 0..7)
#pragma unroll
  for (int i = 0; i < 8; i++) {
    xv[i] = *(const bf16x8*)(xp + (i >> 1) * (Dv * 64) + (i & 1) * 32);
    av[i] = *(const bf16x8*)(ap + (i >> 1) * (Kv * 64) + (i & 1) * 32);
  }
  __builtin_amdgcn_sched_barrier(0);

  // steady: consume group i, refill slot with group i+8
#pragma unroll
  for (int i = 0; i < 8; i++) {
    acc = __builtin_amdgcn_mfma_f32_16x16x32_bf16(xv[i], av[i], acc, 0, 0, 0);
    xv[i] = *(const bf16x8*)(xp + ((i + 8) >> 1) * (Dv * 64) + (i & 1) * 32);
    av[i] = *(const bf16x8*)(ap + ((i + 8) >> 1) * (Kv * 64) + (i & 1) * 32);
    __builtin_amdgcn_sched_barrier(0);
  }

  // drain
#pragma unroll
  for (int i = 0; i < 8; i++)
    acc = __builtin_amdgcn_mfma_f32_16x16x32_bf16(xv[i], av[i], acc, 0, 0, 0);

  if (nh == 1) {
#pragma unroll
    for (int r = 0; r < 4; r++) sred[ksub][lane][r] = acc[r];
  }
  __syncthreads();
  if (nh == 0) {
    const int k = k16 + m;
    const float as = asum[b * Kv + k];
    float ss = 0.f;
#pragma unroll
    for (int r = 0; r < 4; r++) {
      float v = acc[r] + sred[ksub][lane][r];
      int d = d0 + q * 4 + r;
      float val = v - centers[d * Kv + k] * as;
      vlad[((size_t)b * Dv + d) * Kv + k] = val;
      ss = fmaf(val, val, ss);
    }
    ss += __shfl_xor(ss, 16);
    ss += __shfl_xor(ss, 32);
    if (q == 0) atomicAdd(&colsq[b * Kv + k], ss);
  }
}

// ---------------------------------------------------------------------------
// Kernel D: out = vlad * colscale[b,k] * bscale[b]; scales from colsq
// in-block. Grid 4096 x 256.
// ---------------------------------------------------------------------------
__global__ __launch_bounds__(256) void scale_kernel(
    const float* __restrict__ vlad, const float* __restrict__ colsq,
    float* __restrict__ out) {
  const int t = threadIdx.x;
  const size_t i = (size_t)blockIdx.x * 256 + t;
  const int b = (int)(i >> 15);  // D*K = 32768 per b
  __shared__ float scs[64];
  __shared__ float bsh;
  if (t < 64) {
    float tot = colsq[b * Kv + t];
    float sc = 1.0f / fmaxf(sqrtf(tot), EPSv);
    scs[t] = sc;
    float contrib = tot * sc * sc;
#pragma unroll
    for (int off = 32; off > 0; off >>= 1) contrib += __shfl_down(contrib, off);
    if (t == 0) bsh = 1.0f / fmaxf(sqrtf(contrib), EPSv);
  }
  __syncthreads();
  out[i] = vlad[i] * scs[i & 63] * bsh;
}

extern "C" void kernel_launch(void* const* d_in, const int* in_sizes, int n_in,
                              void* d_out, int out_size, void* d_ws, size_t ws_size,
                              hipStream_t stream) {
  const float* x = (const float*)d_in[0];        // [B, D, N]
  const float* w = (const float*)d_in[1];        // [K, D]
  const float* centers = (const float*)d_in[2];  // [D, K]
  float* out = (float*)d_out;                    // [B, D*K]

  char* ws = (char*)d_ws;
  unsigned short* assign = (unsigned short*)ws;               // tiled, 4 MB
  float* vlad = (float*)(ws + 4194304);                       // [B][D][K] fp32, 4 MB
  unsigned short* xbf = (unsigned short*)(ws + 8388608);      // tiled bf16, 32 MB
  unsigned short* wbf = (unsigned short*)(ws + 41943040);     // [K][D] bf16, 64 KB
  float* asum = (float*)(ws + 42008576);                      // B*K
  float* colsq = asum + Bv * Kv;                              // B*K (contiguous)

  hipMemsetAsync(asum, 0, (size_t)2 * Bv * Kv * sizeof(float), stream);

  wconv<<<32, 256, 0, stream>>>(w, wbf);
  fused_scores<<<dim3(Nv / 64, Bv), 512, 0, stream>>>(x, wbf, xbf, assign, asum);
  vlad_mfma<<<dim3(Dv / 16, Bv), 512, 0, stream>>>(xbf, assign, centers, asum, vlad, colsq);
  scale_kernel<<<(Bv * Dv * Kv) / 256, 256, 0, stream>>>(vlad, colsq, out);
}